// Round 8
// baseline (522.992 us; speedup 1.0000x reference)
//
#include <hip/hip_runtime.h>
#include <stdint.h>

// Problem constants
#define NB 4096
#define NT 512
#define OT 513
#define TOTE (NB*OT)          // 2101248 elements per output matrix
#define LOSSOFF (2*TOTE)      // diff_loss slot

typedef float  f32x4 __attribute__((ext_vector_type(4)));
typedef __fp16 f16x8 __attribute__((ext_vector_type(8)));
typedef __fp16 f16x2 __attribute__((ext_vector_type(2)));

#define MFMA(A,B,C) __builtin_amdgcn_mfma_f32_16x16x32_f16((A),(B),(C),0,0,0)

// Barrier that drains LDS only (no vmcnt(0) drain -> global stores stay in flight)
__device__ __forceinline__ void wg_barrier() {
  asm volatile("s_waitcnt lgkmcnt(0)\n\ts_barrier" ::: "memory");
}

__device__ __forceinline__ float fast_tanh(float x) {
  float e = __builtin_amdgcn_exp2f(x * 2.8853900817779268f); // 2*log2(e)
  return __builtin_fmaf(-2.0f, __builtin_amdgcn_rcpf(1.0f + e), 1.0f);
}
__device__ __forceinline__ float fast_silu(float x) {
  float e = __builtin_amdgcn_exp2f(x * -1.4426950408889634f); // -log2(e)
  return x * __builtin_amdgcn_rcpf(1.0f + e);
}
__device__ __forceinline__ uint32_t pk2(float a, float b) {
  union { f16x2 h; uint32_t u; } c;
  c.h = __builtin_amdgcn_cvt_pkrtz(a, b);
  return c.u;
}
__device__ __forceinline__ f16x8 pack8(f32x4 a, f32x4 b) {
  union { f16x8 v; f16x2 h[4]; } u;
  u.h[0] = __builtin_amdgcn_cvt_pkrtz(a.x, a.y);
  u.h[1] = __builtin_amdgcn_cvt_pkrtz(a.z, a.w);
  u.h[2] = __builtin_amdgcn_cvt_pkrtz(b.x, b.y);
  u.h[3] = __builtin_amdgcn_cvt_pkrtz(b.z, b.w);
  return u.v;
}

// Gather one MFMA A-operand fragment directly from a [K][M] row-major f32
// weight matrix.  Identical index math + f32->f16 cast as the old prep_kernel
// (bit-identical fragments -> zero numerics delta vs R7).
__device__ __forceinline__ f16x8 gather_frag(const float* __restrict__ src,
                                             int M, int m, int kb) {
  f16x8 out;
  #pragma unroll
  for (int j = 0; j < 8; j++) out[j] = (__fp16)src[(size_t)(kb + j) * M + m];
  return out;
}

// Compute one dt*U_ext fragment: U_ext[k][m] = dt * sum_i W3[k][i]*[W1|decW|0][i][m]
__device__ __forceinline__ f16x8 compute_ufrag(const float* __restrict__ oW3,
                                               const float* __restrict__ oW1,
                                               const float* __restrict__ dW,
                                               int m, int kb) {
  const float dtc = 1.0f / 512.0f;
  f16x8 out;
  #pragma unroll
  for (int j = 0; j < 8; j++) {
    int k = kb + j;
    float s = 0.f;
    if (m < 128) {
      #pragma unroll 4
      for (int i = 0; i < 64; i++) s = __builtin_fmaf(oW3[k * 64 + i], oW1[i * 128 + m], s);
    } else if (m < 130) {
      for (int i = 0; i < 64; i++) s = __builtin_fmaf(oW3[k * 64 + i], dW[i * 2 + (m - 128)], s);
    }
    out[j] = (__fp16)(s * dtc);
  }
  return out;
}

// ---------------------------------------------------------------------------
// Kernel 0: zero the loss accumulator (d_out poisoned 0xAA before timed runs)
// ---------------------------------------------------------------------------
__global__ void zero_loss_kernel(float* __restrict__ dout) {
  if (threadIdx.x == 0) dout[LOSSOFF] = 0.0f;
}

// ---------------------------------------------------------------------------
// Kernel 1: everything.  256 WGs x 512 threads (8 waves), 16 rows/WG.
// Startup: per-wave direct gather of all needed MFMA fragments from raw
// weights (no prep dispatch, no workspace).  Then prologue (verified R2-R7):
// proj(K=768) -> LN -> +sigma*eps -> denoiser -> z_aug in sZ -> loss.
// Then ODE scan (R5/R7 core): wave w owns M-tile w, wave 7 adds decode tile;
// 2 lgkm-only barriers/step; dt-prescaled U/c with C-operand chaining.
// ---------------------------------------------------------------------------
__global__ __launch_bounds__(512, 1) void main_kernel(
    const float* __restrict__ bert, const float* __restrict__ eps,
    const float* __restrict__ projb, const float* __restrict__ lng,
    const float* __restrict__ lnb,  const float* __restrict__ lns,
    const float* __restrict__ db1,  const float* __restrict__ db2,
    const float* __restrict__ ob1,  const float* __restrict__ ob2,
    const float* __restrict__ decb,
    const float* __restrict__ oW1,  const float* __restrict__ oW2,
    const float* __restrict__ oW3,  const float* __restrict__ ob3,
    const float* __restrict__ dW,   const float* __restrict__ dW1,
    const float* __restrict__ dW2,  const float* __restrict__ pW,
    float* __restrict__ dout) {
  __shared__ __attribute__((aligned(16))) char sZ[16 * 128];   // z f16 [b][64]
  __shared__ __attribute__((aligned(16))) char sH[16 * 256];   // a1 f16 [b][128]
  __shared__ f32x4  sScr[4 * 64];
  __shared__ float2 sMV[64];
  __shared__ float  sLsum[4];
  __shared__ __attribute__((aligned(16))) char sH1[4096];      // h1 f16 [b][128]
  __shared__ __attribute__((aligned(16))) char sH2[4096];      // h2 f16 [b][128]

  const int tid  = threadIdx.x;
  const int wave = tid >> 6, lane = tid & 63;
  const int q = lane >> 4, b = lane & 15;
  const int bg = blockIdx.x * 16 + b;
  const int b7 = b & 7;
  const int u0 = wave * 16 + q * 4;
  const int q8 = q * 8;
  const f32x4 zero4 = {0,0,0,0};
  const float dtc = 1.0f / 512.0f;

  // ---- prologue LDS addressing (8-chunk rows for sZ, 16-chunk for sH) ----
  const int zr0 = b * 128 + ((q    ) ^ b7) * 16;
  const int zr1 = b * 128 + ((q + 4) ^ b7) * 16;
  int hr[4];
  #pragma unroll
  for (int s = 0; s < 4; s++) hr[s] = b * 256 + ((4 * s + q) ^ b7) * 16;
  const int hw = b * 256 + (((2 * wave + (q >> 1)) ^ b7) * 16) + (q & 1) * 8;
  const int zw = b * 128 + (((2 * (wave & 3) + (q >> 1)) ^ b7) * 16) + (q & 1) * 8;

  // ================= PROLOGUE (verified; frags gathered inline) =============
  {
    const int mt = wave & 3, kh = wave >> 2;
    f32x4 hA = {0,0,0,0}, hB = {0,0,0,0};
    #pragma unroll 4
    for (int i = 0; i < 12; i++) {
      int kt = kh * 12 + i;
      f16x8 af = gather_frag(pW, 64, mt * 16 + b, kt * 32 + q8);
      const float* bp = bert + (size_t)bg * 768 + kt * 32 + q8;
      f32x4 f0 = *(const f32x4*)bp;
      f32x4 f1 = *(const f32x4*)(bp + 4);
      f16x8 bf = pack8(f0, f1);
      if (i & 1) hB = MFMA(af, bf, hB); else hA = MFMA(af, bf, hA);
    }
    f32x4 hacc = hA + hB;
    if (wave >= 4) sScr[(wave - 4) * 64 + lane] = hacc;
    __syncthreads();

    f32x4 h = {0,0,0,0}, zc = {0,0,0,0};
    if (wave < 4) {
      h = hacc + sScr[wave * 64 + lane];
      h.x += projb[u0 + 0]; h.y += projb[u0 + 1];
      h.z += projb[u0 + 2]; h.w += projb[u0 + 3];
      float s1 = h.x + h.y + h.z + h.w;
      float s2 = h.x*h.x + h.y*h.y + h.z*h.z + h.w*h.w;
      s1 += __shfl_xor(s1, 16); s1 += __shfl_xor(s1, 32);
      s2 += __shfl_xor(s2, 16); s2 += __shfl_xor(s2, 32);
      if (q == 0) sMV[wave * 16 + b] = make_float2(s1, s2);
    }
    __syncthreads();
    if (wave < 4) {
      float t1 = 0.f, t2 = 0.f;
      #pragma unroll
      for (int w2 = 0; w2 < 4; w2++) { float2 m = sMV[w2 * 16 + b]; t1 += m.x; t2 += m.y; }
      float mu  = t1 * (1.0f / 64.0f);
      float var = t2 * (1.0f / 64.0f) - mu * mu;
      float rs  = rsqrtf(var + 1e-5f);
      float sigma = logf(1.0f + expf(lns[0]));
      f32x4 e = *(const f32x4*)(eps + (size_t)bg * 64 + u0);
      zc.x = __builtin_fmaf((h.x - mu) * rs, lng[u0+0], lnb[u0+0]);
      zc.y = __builtin_fmaf((h.y - mu) * rs, lng[u0+1], lnb[u0+1]);
      zc.z = __builtin_fmaf((h.z - mu) * rs, lng[u0+2], lnb[u0+2]);
      zc.w = __builtin_fmaf((h.w - mu) * rs, lng[u0+3], lnb[u0+3]);
      f32x4 zn = zc + sigma * e;
      *(uint2*)(sZ + zw) = make_uint2(pk2(zn.x, zn.y), pk2(zn.z, zn.w));
    }
    __syncthreads();
    // den1: a1 = silu(zn @ den_W1 + b1), all 8 waves
    {
      f16x8 w0 = gather_frag(dW1, 128, wave * 16 + b, 0 * 32 + q8);
      f16x8 w1 = gather_frag(dW1, 128, wave * 16 + b, 1 * 32 + q8);
      f16x8 bz0 = *(const f16x8*)(sZ + zr0);
      f16x8 bz1 = *(const f16x8*)(sZ + zr1);
      f32x4 bias = { db1[u0+0], db1[u0+1], db1[u0+2], db1[u0+3] };
      f32x4 acc = MFMA(w0, bz0, bias);
      acc = MFMA(w1, bz1, acc);
      *(uint2*)(sH + hw) = make_uint2(pk2(fast_silu(acc.x), fast_silu(acc.y)),
                                      pk2(fast_silu(acc.z), fast_silu(acc.w)));
    }
    __syncthreads();
    // den2: z_aug = a1 @ den_W2 + b2 (waves 0-3) + loss; za -> sZ (reuse)
    if (wave < 4) {
      f16x8 w0 = gather_frag(dW2, 64, wave * 16 + b, 0 * 32 + q8);
      f16x8 w1 = gather_frag(dW2, 64, wave * 16 + b, 1 * 32 + q8);
      f16x8 w2 = gather_frag(dW2, 64, wave * 16 + b, 2 * 32 + q8);
      f16x8 w3 = gather_frag(dW2, 64, wave * 16 + b, 3 * 32 + q8);
      f16x8 g0 = *(const f16x8*)(sH + hr[0]);
      f16x8 g1 = *(const f16x8*)(sH + hr[1]);
      f16x8 g2 = *(const f16x8*)(sH + hr[2]);
      f16x8 g3 = *(const f16x8*)(sH + hr[3]);
      f32x4 bias = { db2[u0+0], db2[u0+1], db2[u0+2], db2[u0+3] };
      f32x4 aA = MFMA(w0, g0, bias); aA = MFMA(w1, g1, aA);
      f32x4 aB = MFMA(w2, g2, zero4); aB = MFMA(w3, g3, aB);
      f32x4 za = aA + aB;
      *(uint2*)(sZ + zw) = make_uint2(pk2(za.x, za.y), pk2(za.z, za.w));
      f32x4 d = za - zc;
      float sl = d.x*d.x + d.y*d.y + d.z*d.z + d.w*d.w;
      const int offs[6] = {1, 2, 4, 8, 16, 32};
      #pragma unroll
      for (int i = 0; i < 6; i++) sl += __shfl_xor(sl, offs[i]);
      if (lane == 0) sLsum[wave] = sl;
    }
    __syncthreads();
    if (tid == 0)
      atomicAdd(dout + LOSSOFF,
                (sLsum[0] + sLsum[1] + sLsum[2] + sLsum[3]) * (1.0f / 262144.0f));
  }

  // ================= ODE SETUP: gather/compute persistent fragments =========
  int rd[4];
  #pragma unroll
  for (int kt = 0; kt < 4; kt++) rd[kt] = b * 256 + (((kt * 4 + q) ^ b) * 16);
  const int wr = b * 256 + (((wave * 2 + (q >> 1)) ^ b) * 16) + (q & 1) * 8;

  f16x8 w2f[4], uf[4], uf8[4];
  #pragma unroll
  for (int kt = 0; kt < 4; kt++) {
    w2f[kt] = gather_frag(oW2, 128, wave * 16 + b, kt * 32 + q8);
    uf [kt] = compute_ufrag(oW3, oW1, dW, wave * 16 + b, kt * 32 + q8);
  }
  if (wave == 7) {
    #pragma unroll
    for (int kt = 0; kt < 4; kt++)
      uf8[kt] = compute_ufrag(oW3, oW1, dW, 128 + b, kt * 32 + q8);  // decode tile
  }
  const f32x4 b2f = *(const f32x4*)(ob2 + wave * 16 + q * 4);
  f32x4 cw, c8;
  #pragma unroll
  for (int r = 0; r < 4; r++) {                // cw = dt*(b3@W1) for this lane
    int u = wave * 16 + q * 4 + r;
    float s = 0.f;
    for (int k = 0; k < 64; k++) s = __builtin_fmaf(ob3[k], oW1[k * 128 + u], s);
    cw[r] = s * dtc;
    int m = 128 + q * 4 + r;                   // c8 = dt*[b3@decW | 0]
    float s8 = 0.f;
    if (m < 130) for (int k = 0; k < 64; k++) s8 = __builtin_fmaf(ob3[k], dW[k * 2 + (m - 128)], s8);
    c8[r] = s8 * dtc;
  }

  // init: G = z@W1 + b1 ; Gd = z@decW + decb ; h1_0 -> sH1 ; store p0
  f16x8 zf0 = *(const f16x8*)(sZ + zr0);
  f16x8 zf1 = *(const f16x8*)(sZ + zr1);
  f32x4 b1v = *(const f32x4*)(ob1 + wave * 16 + q * 4);
  f32x4 G = MFMA(gather_frag(oW1, 128, wave * 16 + b, 0 * 32 + q8), zf0, b1v);
  G = MFMA(gather_frag(oW1, 128, wave * 16 + b, 1 * 32 + q8), zf1, G);
  *(uint2*)(sH1 + wr) = make_uint2(pk2(fast_tanh(G.x), fast_tanh(G.y)),
                                   pk2(fast_tanh(G.z), fast_tanh(G.w)));

  f32x4 Gd = zero4;
  float* const outp_p = dout + (size_t)bg * OT;
  float* const outp_s = dout + (size_t)TOTE + (size_t)bg * OT;
  if (wave == 7) {
    f16x8 d0, d1;                              // decW^T frags: A[m][k]=decW[k][m]
    #pragma unroll
    for (int j = 0; j < 8; j++) {
      d0[j] = (b < 2) ? (__fp16)dW[(0 * 32 + q8 + j) * 2 + b] : (__fp16)0.f;
      d1[j] = (b < 2) ? (__fp16)dW[(1 * 32 + q8 + j) * 2 + b] : (__fp16)0.f;
    }
    f32x4 b1d = zero4;
    if (q == 0) { b1d.x = decb[0]; b1d.y = decb[1]; }
    Gd = MFMA(d0, zf0, b1d);
    Gd = MFMA(d1, zf1, Gd);
    if (q == 0) { outp_p[0] = Gd.x; outp_s[0] = Gd.y; }
  }
  wg_barrier();

  // ================= ODE LOOP =================
  #pragma unroll 2
  for (int t = 0; t < NT; ++t) {
    // ---- phase A: h2 = tanh(h1@W2 + b2) -> sH2 ----
    f16x8 p0 = *(const f16x8*)(sH1 + rd[0]);
    f16x8 p1 = *(const f16x8*)(sH1 + rd[1]);
    f16x8 p2 = *(const f16x8*)(sH1 + rd[2]);
    f16x8 p3 = *(const f16x8*)(sH1 + rd[3]);
    f32x4 a  = MFMA(w2f[0], p0, b2f);
    a  = MFMA(w2f[1], p1, a);
    f32x4 a2 = MFMA(w2f[2], p2, zero4);
    a2 = MFMA(w2f[3], p3, a2);
    f32x4 hv = a + a2;
    *(uint2*)(sH2 + wr) = make_uint2(pk2(fast_tanh(hv.x), fast_tanh(hv.y)),
                                     pk2(fast_tanh(hv.z), fast_tanh(hv.w)));
    wg_barrier();

    // ---- phase B: G = h2@(dt*U) + G + dt*c (C-chained); wave7 decode ----
    f16x8 g0 = *(const f16x8*)(sH2 + rd[0]);
    f16x8 g1 = *(const f16x8*)(sH2 + rd[1]);
    f16x8 g2 = *(const f16x8*)(sH2 + rd[2]);
    f16x8 g3 = *(const f16x8*)(sH2 + rd[3]);
    f32x4 d  = MFMA(uf[0], g0, G);
    d  = MFMA(uf[1], g1, d);
    f32x4 d2 = MFMA(uf[2], g2, cw);
    d2 = MFMA(uf[3], g3, d2);
    G = d + d2;
    *(uint2*)(sH1 + wr) = make_uint2(pk2(fast_tanh(G.x), fast_tanh(G.y)),
                                     pk2(fast_tanh(G.z), fast_tanh(G.w)));
    if (wave == 7) {
      f32x4 e  = MFMA(uf8[0], g0, Gd);
      e  = MFMA(uf8[1], g1, e);
      f32x4 e2 = MFMA(uf8[2], g2, c8);
      e2 = MFMA(uf8[3], g3, e2);
      Gd = e + e2;
      if (q == 0) { outp_p[t + 1] = Gd.x; outp_s[t + 1] = Gd.y; }
    }
    wg_barrier();
  }
}

// ---------------------------------------------------------------------------
extern "C" void kernel_launch(void* const* d_in, const int* in_sizes, int n_in,
                              void* d_out, int out_size, void* d_ws, size_t ws_size,
                              hipStream_t stream) {
  const float* bert  = (const float*)d_in[0];
  const float* eps   = (const float*)d_in[3];
  const float* projW = (const float*)d_in[4];
  const float* projb = (const float*)d_in[5];
  const float* lng   = (const float*)d_in[6];
  const float* lnb   = (const float*)d_in[7];
  const float* lns   = (const float*)d_in[8];
  const float* denW1 = (const float*)d_in[9];
  const float* denb1 = (const float*)d_in[10];
  const float* denW2 = (const float*)d_in[11];
  const float* denb2 = (const float*)d_in[12];
  const float* odeW1 = (const float*)d_in[13];
  const float* odeb1 = (const float*)d_in[14];
  const float* odeW2 = (const float*)d_in[15];
  const float* odeb2 = (const float*)d_in[16];
  const float* odeW3 = (const float*)d_in[17];
  const float* odeb3 = (const float*)d_in[18];
  const float* decW  = (const float*)d_in[19];
  const float* decb  = (const float*)d_in[20];
  float* dout = (float*)d_out;

  zero_loss_kernel<<<1, 64, 0, stream>>>(dout);
  main_kernel<<<256, 512, 0, stream>>>(bert, eps, projb, lng, lnb, lns,
                                       denb1, denb2, odeb1, odeb2, decb,
                                       odeW1, odeW2, odeW3, odeb3,
                                       decW, denW1, denW2, projW, dout);
}

// Round 9
// 433.157 us; speedup vs baseline: 1.2074x; 1.2074x over previous
//
#include <hip/hip_runtime.h>
#include <stdint.h>

// Problem constants
#define NB 4096
#define NT 512
#define OT 513
#define TOTE (NB*OT)          // 2101248 elements per output matrix
#define LOSSOFF (2*TOTE)      // diff_loss slot

typedef float  f32x4 __attribute__((ext_vector_type(4)));
typedef __fp16 f16x8 __attribute__((ext_vector_type(8)));
typedef __fp16 f16x2 __attribute__((ext_vector_type(2)));

#define MFMA(A,B,C) __builtin_amdgcn_mfma_f32_16x16x32_f16((A),(B),(C),0,0,0)

// Barrier that drains LDS only (no vmcnt(0) drain -> global stores stay in flight)
__device__ __forceinline__ void wg_barrier() {
  asm volatile("s_waitcnt lgkmcnt(0)\n\ts_barrier" ::: "memory");
}

__device__ __forceinline__ float fast_tanh(float x) {
  float e = __builtin_amdgcn_exp2f(x * 2.8853900817779268f); // 2*log2(e)
  return __builtin_fmaf(-2.0f, __builtin_amdgcn_rcpf(1.0f + e), 1.0f);
}
__device__ __forceinline__ float fast_silu(float x) {
  float e = __builtin_amdgcn_exp2f(x * -1.4426950408889634f); // -log2(e)
  return x * __builtin_amdgcn_rcpf(1.0f + e);
}
__device__ __forceinline__ uint32_t pk2(float a, float b) {
  union { f16x2 h; uint32_t u; } c;
  c.h = __builtin_amdgcn_cvt_pkrtz(a, b);
  return c.u;
}
__device__ __forceinline__ f16x8 pack8(f32x4 a, f32x4 b) {
  union { f16x8 v; f16x2 h[4]; } u;
  u.h[0] = __builtin_amdgcn_cvt_pkrtz(a.x, a.y);
  u.h[1] = __builtin_amdgcn_cvt_pkrtz(a.z, a.w);
  u.h[2] = __builtin_amdgcn_cvt_pkrtz(b.x, b.y);
  u.h[3] = __builtin_amdgcn_cvt_pkrtz(b.z, b.w);
  return u.v;
}

// ws layout (bytes):
//   [0, 228K)   wpak : packed A-frags (228 frags x 1 KB)
//   [256K, +576B) cbuf : dt * [b3@W1 (128) | b3@decW (2) | 0 (14)]
#define WS_CBUF (256u<<10)

// ---------------------------------------------------------------------------
// Kernel A: prep — packs ALL weights into MFMA A-operand f16 fragments and
// computes dt*U_ext inline.  ONE small dispatch: amortized, coalesced-ish,
// runs once (R8 showed per-WG recompute costs +115us/WG in uncoalesced
// gathers — do NOT fuse this into main).
// Frag layout: A[m=lane&15][k=kt*32+(lane>>4)*8+j], 1 KB per frag.
//   [0,16)  ode_W1 (M=128,Kt=2)   [16,48)  ode_W2 (M=128,Kt=4)
//   [48,50) decW^T (M=16[2 real],Kt=2)     [50,64)  unused
//   [64,80) den_W1 (M=128,Kt=2)   [80,96)  den_W2 (M=64,Kt=4)
//   [96,192) proj_W (M=64,Kt=24)  [192,228) dt*U_ext (M=144,Kt=4)
// U_ext[k][m] = dt * sum_i W3[k][i] * [W1|decW|0][i][m]  (k=h2-unit)
// Block 57: cbuf (dt-prescaled c_ext) + zero the loss slot.
// Grid 58 x 256.
// ---------------------------------------------------------------------------
__global__ void prep_kernel(const float* __restrict__ oW1, const float* __restrict__ oW2,
                            const float* __restrict__ dW,  const float* __restrict__ dW1,
                            const float* __restrict__ dW2, const float* __restrict__ pW,
                            const float* __restrict__ oW3, const float* __restrict__ ob3,
                            char* __restrict__ wdst, float* __restrict__ cbuf,
                            float* __restrict__ dout) {
  const float dtc = 1.0f / 512.0f;
  if (blockIdx.x == 57) {             // c_ext + loss zero
    int tid = threadIdx.x;
    if (tid < 144) {
      float s = 0.f;
      if (tid < 128) {
        for (int k = 0; k < 64; k++) s = __builtin_fmaf(ob3[k], oW1[k * 128 + tid], s);
      } else if (tid < 130) {
        int cc = tid - 128;
        for (int k = 0; k < 64; k++) s = __builtin_fmaf(ob3[k], dW[k * 2 + cc], s);
      }
      cbuf[tid] = s * dtc;
    }
    if (tid == 255) dout[LOSSOFF] = 0.0f;
    return;
  }
  int g = blockIdx.x * 256 + threadIdx.x;
  int fid = g >> 6, lane = g & 63;
  if (fid >= 50 && fid < 64) return;
  int m4 = lane & 15;
  int k0 = (lane >> 4) * 8;           // within-frag k base (adds kt*32 below)
  if (fid >= 48 && fid < 50) {        // decW^T (unscaled; Gd init only)
    int kt = fid - 48;
    int kb = kt * 32 + k0;
    f16x8 out;
    #pragma unroll
    for (int j = 0; j < 8; j++) out[j] = (m4 < 2) ? (__fp16)dW[(kb + j) * 2 + m4] : (__fp16)0.f;
    *(f16x8*)(wdst + (size_t)(fid * 64 + lane) * 16) = out;
    return;
  }
  if (fid >= 192) {                   // dt*U_ext computed inline
    int local = fid - 192;
    int mt = local >> 2, kt = local & 3;
    int m  = mt * 16 + m4;
    int kb = kt * 32 + k0;
    f16x8 out;
    #pragma unroll
    for (int j = 0; j < 8; j++) {
      int k = kb + j;
      float s = 0.f;
      if (m < 128) {
        #pragma unroll 4
        for (int i = 0; i < 64; i++) s = __builtin_fmaf(oW3[k * 64 + i], oW1[i * 128 + m], s);
      } else if (m < 130) {
        for (int i = 0; i < 64; i++) s = __builtin_fmaf(oW3[k * 64 + i], dW[i * 2 + (m - 128)], s);
      }
      out[j] = (__fp16)(s * dtc);
    }
    *(f16x8*)(wdst + (size_t)(fid * 64 + lane) * 16) = out;
    return;
  }
  const float* src; int Kt, M, base;
  if      (fid < 16)  { src = oW1;  Kt = 2;  M = 128; base = 0;  }
  else if (fid < 48)  { src = oW2;  Kt = 4;  M = 128; base = 16; }
  else if (fid < 80)  { src = dW1;  Kt = 2;  M = 128; base = 64; }
  else if (fid < 96)  { src = dW2;  Kt = 4;  M = 64;  base = 80; }
  else                { src = pW;   Kt = 24; M = 64;  base = 96; }
  int local = fid - base;
  int mt = local / Kt, kt = local % Kt;
  int m  = mt * 16 + m4;
  int kb = kt * 32 + k0;
  f16x8 out;
  #pragma unroll
  for (int j = 0; j < 8; j++) out[j] = (__fp16)src[(size_t)(kb + j) * M + m];
  *(f16x8*)(wdst + (size_t)(fid * 64 + lane) * 16) = out;
}

// ---------------------------------------------------------------------------
// Kernel B: fused prologue + ODE scan.  256 WGs x 512 threads (8 waves),
// 16 rows/WG.  Prologue (verified R2-R7): proj(MFMA,K=768) -> LN -> +sigma*eps
// -> denoiser -> z_aug (handed off via sZ in LDS, no global round trip) ->
// diff_loss atomicAdd.  ODE core = R5 structure (proven 330us): wave w owns
// M-tile w, wave 7 also owns decode tile 8; 2 lgkm-only barriers/step;
// dt-prescaled U/c let phase B chain C-operands: G = MFMA..(C=G) + MFMA..(C=dt*c).
// ---------------------------------------------------------------------------
__global__ __launch_bounds__(512, 1) void main_kernel(
    const float* __restrict__ bert, const float* __restrict__ eps,
    const float* __restrict__ projb, const float* __restrict__ lng,
    const float* __restrict__ lnb,  const float* __restrict__ lns,
    const float* __restrict__ db1,  const float* __restrict__ db2,
    const float* __restrict__ ob1,  const float* __restrict__ ob2,
    const float* __restrict__ decb, const char* __restrict__ wpack,
    const float* __restrict__ cbuf, float* __restrict__ dout) {
  __shared__ __attribute__((aligned(16))) char sZ[16 * 128];   // z f16 [b][64]
  __shared__ __attribute__((aligned(16))) char sH[16 * 256];   // a1 f16 [b][128]
  __shared__ f32x4  sScr[4 * 64];
  __shared__ float2 sMV[64];
  __shared__ float  sLsum[4];
  __shared__ __attribute__((aligned(16))) char sH1[4096];      // h1 f16 [b][128]
  __shared__ __attribute__((aligned(16))) char sH2[4096];      // h2 f16 [b][128]

  const int tid  = threadIdx.x;
  const int wave = tid >> 6, lane = tid & 63;
  const int q = lane >> 4, b = lane & 15;
  const int bg = blockIdx.x * 16 + b;
  const int b7 = b & 7;
  const f16x8* wp = (const f16x8*)wpack;
  const int u0 = wave * 16 + q * 4;
  const f32x4 zero4 = {0,0,0,0};

  // ---- prologue LDS addressing (8-chunk rows for sZ, 16-chunk for sH) ----
  const int zr0 = b * 128 + ((q    ) ^ b7) * 16;
  const int zr1 = b * 128 + ((q + 4) ^ b7) * 16;
  int hr[4];
  #pragma unroll
  for (int s = 0; s < 4; s++) hr[s] = b * 256 + ((4 * s + q) ^ b7) * 16;
  const int hw = b * 256 + (((2 * wave + (q >> 1)) ^ b7) * 16) + (q & 1) * 8;
  const int zw = b * 128 + (((2 * (wave & 3) + (q >> 1)) ^ b7) * 16) + (q & 1) * 8;

  // ================= PROLOGUE (verified) =================
  {
    const int mt = wave & 3, kh = wave >> 2;
    f32x4 hA = {0,0,0,0}, hB = {0,0,0,0};
    #pragma unroll 4
    for (int i = 0; i < 12; i++) {
      int kt = kh * 12 + i;
      f16x8 af = wp[(size_t)(96 + mt * 24 + kt) * 64 + lane];
      const float* bp = bert + (size_t)bg * 768 + kt * 32 + q * 8;
      f32x4 f0 = *(const f32x4*)bp;
      f32x4 f1 = *(const f32x4*)(bp + 4);
      f16x8 bf = pack8(f0, f1);
      if (i & 1) hB = MFMA(af, bf, hB); else hA = MFMA(af, bf, hA);
    }
    f32x4 hacc = hA + hB;
    if (wave >= 4) sScr[(wave - 4) * 64 + lane] = hacc;
    __syncthreads();

    f32x4 h = {0,0,0,0}, zc = {0,0,0,0};
    if (wave < 4) {
      h = hacc + sScr[wave * 64 + lane];
      h.x += projb[u0 + 0]; h.y += projb[u0 + 1];
      h.z += projb[u0 + 2]; h.w += projb[u0 + 3];
      float s1 = h.x + h.y + h.z + h.w;
      float s2 = h.x*h.x + h.y*h.y + h.z*h.z + h.w*h.w;
      s1 += __shfl_xor(s1, 16); s1 += __shfl_xor(s1, 32);
      s2 += __shfl_xor(s2, 16); s2 += __shfl_xor(s2, 32);
      if (q == 0) sMV[wave * 16 + b] = make_float2(s1, s2);
    }
    __syncthreads();
    if (wave < 4) {
      float t1 = 0.f, t2 = 0.f;
      #pragma unroll
      for (int w2 = 0; w2 < 4; w2++) { float2 m = sMV[w2 * 16 + b]; t1 += m.x; t2 += m.y; }
      float mu  = t1 * (1.0f / 64.0f);
      float var = t2 * (1.0f / 64.0f) - mu * mu;
      float rs  = rsqrtf(var + 1e-5f);
      float sigma = logf(1.0f + expf(lns[0]));
      f32x4 e = *(const f32x4*)(eps + (size_t)bg * 64 + u0);
      zc.x = __builtin_fmaf((h.x - mu) * rs, lng[u0+0], lnb[u0+0]);
      zc.y = __builtin_fmaf((h.y - mu) * rs, lng[u0+1], lnb[u0+1]);
      zc.z = __builtin_fmaf((h.z - mu) * rs, lng[u0+2], lnb[u0+2]);
      zc.w = __builtin_fmaf((h.w - mu) * rs, lng[u0+3], lnb[u0+3]);
      f32x4 zn = zc + sigma * e;
      *(uint2*)(sZ + zw) = make_uint2(pk2(zn.x, zn.y), pk2(zn.z, zn.w));
    }
    __syncthreads();
    // den1: a1 = silu(zn @ den_W1 + b1), all 8 waves
    {
      f16x8 w0 = wp[(size_t)(64 + wave * 2 + 0) * 64 + lane];
      f16x8 w1 = wp[(size_t)(64 + wave * 2 + 1) * 64 + lane];
      f16x8 bz0 = *(const f16x8*)(sZ + zr0);
      f16x8 bz1 = *(const f16x8*)(sZ + zr1);
      f32x4 bias = { db1[u0+0], db1[u0+1], db1[u0+2], db1[u0+3] };
      f32x4 acc = MFMA(w0, bz0, bias);
      acc = MFMA(w1, bz1, acc);
      *(uint2*)(sH + hw) = make_uint2(pk2(fast_silu(acc.x), fast_silu(acc.y)),
                                      pk2(fast_silu(acc.z), fast_silu(acc.w)));
    }
    __syncthreads();
    // den2: z_aug = a1 @ den_W2 + b2 (waves 0-3) + loss; za -> sZ (reuse)
    if (wave < 4) {
      f16x8 w0 = wp[(size_t)(80 + wave * 4 + 0) * 64 + lane];
      f16x8 w1 = wp[(size_t)(80 + wave * 4 + 1) * 64 + lane];
      f16x8 w2 = wp[(size_t)(80 + wave * 4 + 2) * 64 + lane];
      f16x8 w3 = wp[(size_t)(80 + wave * 4 + 3) * 64 + lane];
      f16x8 g0 = *(const f16x8*)(sH + hr[0]);
      f16x8 g1 = *(const f16x8*)(sH + hr[1]);
      f16x8 g2 = *(const f16x8*)(sH + hr[2]);
      f16x8 g3 = *(const f16x8*)(sH + hr[3]);
      f32x4 bias = { db2[u0+0], db2[u0+1], db2[u0+2], db2[u0+3] };
      f32x4 aA = MFMA(w0, g0, bias); aA = MFMA(w1, g1, aA);
      f32x4 aB = MFMA(w2, g2, zero4); aB = MFMA(w3, g3, aB);
      f32x4 za = aA + aB;
      *(uint2*)(sZ + zw) = make_uint2(pk2(za.x, za.y), pk2(za.z, za.w));
      f32x4 d = za - zc;
      float sl = d.x*d.x + d.y*d.y + d.z*d.z + d.w*d.w;
      const int offs[6] = {1, 2, 4, 8, 16, 32};
      #pragma unroll
      for (int i = 0; i < 6; i++) sl += __shfl_xor(sl, offs[i]);
      if (lane == 0) sLsum[wave] = sl;
    }
    __syncthreads();
    if (tid == 0)
      atomicAdd(dout + LOSSOFF,
                (sLsum[0] + sLsum[1] + sLsum[2] + sLsum[3]) * (1.0f / 262144.0f));
  }

  // ================= ODE SCAN (R5 core + prescale chaining) =================
  // 16-chunk row addressing for sH1/sH2
  int rd[4];
  #pragma unroll
  for (int kt = 0; kt < 4; kt++) rd[kt] = b * 256 + (((kt * 4 + q) ^ b) * 16);
  const int wr = b * 256 + (((wave * 2 + (q >> 1)) ^ b) * 16) + (q & 1) * 8;

  // Persistent weight fragments
  f16x8 w2f[4], uf[4], uf8[4];
  #pragma unroll
  for (int kt = 0; kt < 4; kt++) {
    w2f[kt] = wp[(size_t)(16  + wave * 4 + kt) * 64 + lane];
    uf [kt] = wp[(size_t)(192 + wave * 4 + kt) * 64 + lane];
  }
  if (wave == 7) {
    #pragma unroll
    for (int kt = 0; kt < 4; kt++)
      uf8[kt] = wp[(size_t)(192 + 32 + kt) * 64 + lane];          // dt*U_ext tile 8
  }
  const f32x4 b2f = *(const f32x4*)(ob2  + wave * 16 + q * 4);
  const f32x4 cw  = *(const f32x4*)(cbuf + wave * 16 + q * 4);    // dt*(b3@W1)
  const f32x4 c8  = *(const f32x4*)(cbuf + 128 + q * 4);          // dt*[cv|0]

  // init: G = z@W1 + b1 ; Gd = z@decW + decb ; h1_0 -> sH1 ; store p0
  f16x8 zf0 = *(const f16x8*)(sZ + zr0);
  f16x8 zf1 = *(const f16x8*)(sZ + zr1);
  f32x4 b1v = *(const f32x4*)(ob1 + wave * 16 + q * 4);
  f32x4 G = MFMA(wp[(size_t)(wave * 2 + 0) * 64 + lane], zf0, b1v);
  G = MFMA(wp[(size_t)(wave * 2 + 1) * 64 + lane], zf1, G);
  *(uint2*)(sH1 + wr) = make_uint2(pk2(fast_tanh(G.x), fast_tanh(G.y)),
                                   pk2(fast_tanh(G.z), fast_tanh(G.w)));

  f32x4 Gd = zero4;
  float* const outp_p = dout + (size_t)bg * OT;
  float* const outp_s = dout + (size_t)TOTE + (size_t)bg * OT;
  if (wave == 7) {
    f32x4 b1d = zero4;
    if (q == 0) { b1d.x = decb[0]; b1d.y = decb[1]; }
    Gd = MFMA(wp[(size_t)48 * 64 + lane], zf0, b1d);
    Gd = MFMA(wp[(size_t)49 * 64 + lane], zf1, Gd);
    if (q == 0) { outp_p[0] = Gd.x; outp_s[0] = Gd.y; }
  }
  wg_barrier();

  #pragma unroll 1
  for (int t = 0; t < NT; ++t) {
    // ---- phase A: h2 = tanh(h1@W2 + b2) -> sH2 ----
    f16x8 p0 = *(const f16x8*)(sH1 + rd[0]);
    f16x8 p1 = *(const f16x8*)(sH1 + rd[1]);
    f16x8 p2 = *(const f16x8*)(sH1 + rd[2]);
    f16x8 p3 = *(const f16x8*)(sH1 + rd[3]);
    f32x4 a  = MFMA(w2f[0], p0, b2f);
    a  = MFMA(w2f[1], p1, a);
    f32x4 a2 = MFMA(w2f[2], p2, zero4);
    a2 = MFMA(w2f[3], p3, a2);
    f32x4 hv = a + a2;
    *(uint2*)(sH2 + wr) = make_uint2(pk2(fast_tanh(hv.x), fast_tanh(hv.y)),
                                     pk2(fast_tanh(hv.z), fast_tanh(hv.w)));
    wg_barrier();

    // ---- phase B: G = h2@(dt*U) + G + dt*c (C-chained); wave7 decode ----
    f16x8 g0 = *(const f16x8*)(sH2 + rd[0]);
    f16x8 g1 = *(const f16x8*)(sH2 + rd[1]);
    f16x8 g2 = *(const f16x8*)(sH2 + rd[2]);
    f16x8 g3 = *(const f16x8*)(sH2 + rd[3]);
    f32x4 d  = MFMA(uf[0], g0, G);
    d  = MFMA(uf[1], g1, d);
    f32x4 d2 = MFMA(uf[2], g2, cw);
    d2 = MFMA(uf[3], g3, d2);
    G = d + d2;
    *(uint2*)(sH1 + wr) = make_uint2(pk2(fast_tanh(G.x), fast_tanh(G.y)),
                                     pk2(fast_tanh(G.z), fast_tanh(G.w)));
    if (wave == 7) {
      f32x4 e  = MFMA(uf8[0], g0, Gd);
      e  = MFMA(uf8[1], g1, e);
      f32x4 e2 = MFMA(uf8[2], g2, c8);
      e2 = MFMA(uf8[3], g3, e2);
      Gd = e + e2;
      if (q == 0) { outp_p[t + 1] = Gd.x; outp_s[t + 1] = Gd.y; }
    }
    wg_barrier();
  }
}

// ---------------------------------------------------------------------------
extern "C" void kernel_launch(void* const* d_in, const int* in_sizes, int n_in,
                              void* d_out, int out_size, void* d_ws, size_t ws_size,
                              hipStream_t stream) {
  const float* bert  = (const float*)d_in[0];
  const float* eps   = (const float*)d_in[3];
  const float* projW = (const float*)d_in[4];
  const float* projb = (const float*)d_in[5];
  const float* lng   = (const float*)d_in[6];
  const float* lnb   = (const float*)d_in[7];
  const float* lns   = (const float*)d_in[8];
  const float* denW1 = (const float*)d_in[9];
  const float* denb1 = (const float*)d_in[10];
  const float* denW2 = (const float*)d_in[11];
  const float* denb2 = (const float*)d_in[12];
  const float* odeW1 = (const float*)d_in[13];
  const float* odeb1 = (const float*)d_in[14];
  const float* odeW2 = (const float*)d_in[15];
  const float* odeb2 = (const float*)d_in[16];
  const float* odeW3 = (const float*)d_in[17];
  const float* odeb3 = (const float*)d_in[18];
  const float* decW  = (const float*)d_in[19];
  const float* decb  = (const float*)d_in[20];
  float* dout = (float*)d_out;

  char*  wpak = (char*)d_ws;
  float* cbuf = (float*)((char*)d_ws + WS_CBUF);

  prep_kernel<<<58, 256, 0, stream>>>(odeW1, odeW2, decW, denW1, denW2, projW,
                                      odeW3, odeb3, wpak, cbuf, dout);
  main_kernel<<<256, 512, 0, stream>>>(bert, eps, projb, lng, lnb, lns,
                                       denb1, denb2, odeb1, odeb2, decb,
                                       wpak, cbuf, dout);
}